// Round 5
// baseline (475.984 us; speedup 1.0000x reference)
//
#include <hip/hip_runtime.h>
#include <hip/hip_bf16.h>

#define SLEN 512
#define BATCH 256
#define NIN 300
#define KP 320
#define NG 256
#define NH 64
#define BM 128
#define BN 128
#define BK 64
#define LDP 72   // padded LDS row length (bf16) -> 144B rows, 2-way (free) b128 reads
#define FB 32    // hs flush window (steps)
#define HBP 68   // hbuf padded row (floats): (4j+cc)%32 distinct -> conflict-free flush

typedef float f32x4 __attribute__((ext_vector_type(4)));
typedef short s16x8 __attribute__((ext_vector_type(8)));
typedef short s16x4 __attribute__((ext_vector_type(4)));
typedef _Float16 f16x8 __attribute__((ext_vector_type(8)));
typedef _Float16 f16x2 __attribute__((ext_vector_type(2)));

__device__ __forceinline__ short f2bf(float f) {
  union { float f; unsigned u; } v; v.f = f;
  unsigned r = v.u + 0x7fffu + ((v.u >> 16) & 1u);  // RNE
  return (short)(r >> 16);
}

// Build WcatT[n][k] (bf16, K padded to 320), bcat[n], and Wg16[col][k] = f16(W_glt[k][col]).
__global__ void prep_w(const float* __restrict__ Wpt0, const float* __restrict__ bpt0,
                       const float* __restrict__ Wpt1, const float* __restrict__ bpt1,
                       const float* __restrict__ Wglt,
                       short* __restrict__ WcatT, float* __restrict__ bcat,
                       _Float16* __restrict__ Wg16) {
  int idx = blockIdx.x * 256 + threadIdx.x;
  if (idx < NG * KP) {
    int n = idx / KP, k = idx - n * KP;
    int g = n >> 6, h = n & 63;
    float w = 0.f;
    if (k < NIN) {
      if (h < 32) w = Wpt0[k * 128 + g * 32 + h];
      else        w = 0.5f * Wpt1[(k >> 1) * 128 + g * 32 + (h - 32)];
    }
    WcatT[idx] = f2bf(w);
  }
  if (idx < NG * NH) {  // transpose W_glt (64 x 256) -> Wg16 (256 x 64), f16
    int c = idx >> 6, k = idx & 63;
    Wg16[idx] = (_Float16)Wglt[k * NG + c];
  }
  if (idx < NG) {
    int g = idx >> 6, h = idx & 63;
    bcat[idx] = (h < 32) ? bpt0[g * 32 + h] : bpt1[g * 32 + h - 32];
  }
}

// C[row][n] = bf16(x[row]) @ WcatT^T + bcat   (row-chunk local)
__global__ __launch_bounds__(256) void gemm_i2h(
    const float* __restrict__ x, const short* __restrict__ WcatT,
    const float* __restrict__ bcat, float* __restrict__ C) {
  __shared__ short As[BM][LDP];
  __shared__ short Bs[BN][LDP];
  const int tid = threadIdx.x;
  const int m0 = blockIdx.x * BM;
  const int n0 = blockIdx.y * BN;
  const int lane = tid & 63;
  const int w = tid >> 6;
  const int wr = w >> 1, wc = w & 1;

  f32x4 acc[4][4];
#pragma unroll
  for (int m = 0; m < 4; ++m)
#pragma unroll
    for (int n = 0; n < 4; ++n) acc[m][n] = (f32x4){0.f, 0.f, 0.f, 0.f};

  const int arow_l = tid >> 4;        // 0..15
  const int acol   = (tid & 15) * 4;  // 0..60
  const int brow_l = tid >> 3;        // 0..31
  const int bcol   = (tid & 7) * 8;   // 0..56

  for (int k0 = 0; k0 < KP; k0 += BK) {
#pragma unroll
    for (int p = 0; p < 8; ++p) {
      int row = p * 16 + arow_l;
      int gk = k0 + acol;
      f32x4 v = (f32x4){0.f, 0.f, 0.f, 0.f};
      if (gk + 3 < NIN)  // 300 = 4*75 so vectors never straddle the boundary
        v = *reinterpret_cast<const f32x4*>(&x[(size_t)(m0 + row) * NIN + gk]);
      s16x4 sv;
      sv[0] = f2bf(v[0]); sv[1] = f2bf(v[1]); sv[2] = f2bf(v[2]); sv[3] = f2bf(v[3]);
      *reinterpret_cast<s16x4*>(&As[row][acol]) = sv;
    }
#pragma unroll
    for (int p = 0; p < 4; ++p) {
      int n = p * 32 + brow_l;
      s16x8 v = *reinterpret_cast<const s16x8*>(&WcatT[(size_t)(n0 + n) * KP + k0 + bcol]);
      *reinterpret_cast<s16x8*>(&Bs[n][bcol]) = v;
    }
    __syncthreads();
#pragma unroll
    for (int ks = 0; ks < 2; ++ks) {
      const int kk = ks * 32 + (lane >> 4) * 8;
      s16x8 a[4], b[4];
#pragma unroll
      for (int m = 0; m < 4; ++m)
        a[m] = *reinterpret_cast<const s16x8*>(&As[wr * 64 + m * 16 + (lane & 15)][kk]);
#pragma unroll
      for (int n = 0; n < 4; ++n)
        b[n] = *reinterpret_cast<const s16x8*>(&Bs[wc * 64 + n * 16 + (lane & 15)][kk]);
#pragma unroll
      for (int m = 0; m < 4; ++m)
#pragma unroll
        for (int n = 0; n < 4; ++n)
          acc[m][n] = __builtin_amdgcn_mfma_f32_16x16x32_bf16(a[m], b[n], acc[m][n], 0, 0, 0);
    }
    __syncthreads();
  }
  const int fc = lane & 15;
  const int fr = (lane >> 4) * 4;
#pragma unroll
  for (int n = 0; n < 4; ++n) {
    int col = n0 + wc * 64 + n * 16 + fc;
    float bias = bcat[col];
#pragma unroll
    for (int m = 0; m < 4; ++m) {
#pragma unroll
      for (int r = 0; r < 4; ++r) {
        int row = m0 + wr * 64 + m * 16 + fr + r;
        C[(size_t)row * NG + col] = acc[m][n][r] + bias;
      }
    }
  }
}

// One workgroup (256 thr = 4 waves) per batch row, 1 block/CU.
// Wave w, lane l: gate g = l>>4, hidden hidx = 16w + (l&15), gate column = g*64+hidx.
// Weights: 8 named f16x8 (32 VGPRs) -> total regs fit under the default 64-reg
// occupancy budget: no spill, no scratch. Dot via v_dot2_f32_f16 (f32 accum).
// h kept in LDS as f16 (halved broadcast traffic). One raw barrier per step
// (lgkmcnt only -> hs stores / i2h prefetch stay in flight).
__global__ __launch_bounds__(256, 1)
void rec_seq(
    const float* __restrict__ i2h, const _Float16* __restrict__ Wg16,
    const float* __restrict__ h_in, const float* __restrict__ c_in,
    float* __restrict__ h_state, float* __restrict__ c_state,
    float* __restrict__ hs_out, float* __restrict__ hT_out, float* __restrict__ cT_out,
    int T, int is_last) {
  const int b = blockIdx.x;
  const int tid = threadIdx.x;
  const int w = tid >> 6;
  const int l = tid & 63;
  const int g = l >> 4;
  const int hidx = w * 16 + (l & 15);
  const int col = g * 64 + hidx;
  __shared__ f16x8 h_lds[2][8];            // h as f16, 2 buffers x 64
  __shared__ float hbuf[2][FB][HBP];       // hs batching window, padded rows

  const f16x8* wp = reinterpret_cast<const f16x8*>(Wg16 + (size_t)col * NH);
#define LOADW(i) f16x8 w##i = wp[i];
  LOADW(0) LOADW(1) LOADW(2) LOADW(3) LOADW(4) LOADW(5) LOADW(6) LOADW(7)
#define PIN(i) asm volatile("" : "+v"(w##i));
  PIN(0) PIN(1) PIN(2) PIN(3) PIN(4) PIN(5) PIN(6) PIN(7)

  float creg = 0.f;
  if (l < 16) creg = c_in[b * NH + hidx];
  if (tid < NH) reinterpret_cast<_Float16*>(h_lds[0])[tid] = (_Float16)h_in[b * NH + tid];
  __syncthreads();

  const float* ip = i2h + (size_t)b * NG + col;
  float cur = ip[0];
  float nxt = (T > 1) ? ip[(size_t)NG * BATCH] : 0.f;
  const float mm = (g == 1) ? 2.f : 1.f;

  for (int s = 0; s < T; ++s) {
    float fut = 0.f;
    if (s + 2 < T) fut = ip[(size_t)(s + 2) * NG * BATCH];  // stays in flight across barrier

    const f16x8* hb = h_lds[s & 1];
    float acc0 = 0.f, acc1 = 0.f;
#define PAIR(v, j) __builtin_shufflevector(v, v, 2*(j), 2*(j)+1)
#define DOT(i, A0, A1) { f16x8 hv = hb[i]; \
      A0 = __builtin_amdgcn_fdot2(PAIR(hv,0), PAIR(w##i,0), A0, false); \
      A1 = __builtin_amdgcn_fdot2(PAIR(hv,1), PAIR(w##i,1), A1, false); \
      A0 = __builtin_amdgcn_fdot2(PAIR(hv,2), PAIR(w##i,2), A0, false); \
      A1 = __builtin_amdgcn_fdot2(PAIR(hv,3), PAIR(w##i,3), A1, false); }
    DOT(0, acc0, acc1) DOT(1, acc0, acc1) DOT(2, acc0, acc1) DOT(3, acc0, acc1)
    DOT(4, acc0, acc1) DOT(5, acc0, acc1) DOT(6, acc0, acc1) DOT(7, acc0, acc1)
    float pre = cur + (acc0 + acc1);

    // sigmoid for f,i,o; tanh (=2*sigmoid(2x)-1) for g; one exp either way
    float xx = fminf(fmaxf(pre, -30.f), 30.f);
    float e = __expf(-mm * xx);
    float y = 1.f / (1.f + e);
    float act = (g == 1) ? (2.f * y - 1.f) : y;

    // lanes 0..15 (g==0, holding f) gather g,i,o from lanes +16,+32,+48
    float g_ = __shfl(act, l + 16);
    float i_ = __shfl(act, l + 32);
    float o_ = __shfl(act, l + 48);

    if (l < 16) {
      float c1 = act * creg + i_ * g_;
      creg = c1;
      float ct = fminf(fmaxf(c1, -15.f), 15.f);
      float e2 = __expf(-2.f * ct);
      float th = (1.f - e2) / (1.f + e2);
      float h1 = o_ * th;
      reinterpret_cast<_Float16*>(h_lds[(s + 1) & 1])[hidx] = (_Float16)h1;
      hbuf[(s >> 5) & 1][s & (FB - 1)][hidx] = h1;
    }
    // order the ds_writes only; global stores/prefetch stay outstanding
    asm volatile("s_waitcnt lgkmcnt(0)" ::: "memory");
    __builtin_amdgcn_s_barrier();

    // bulk flush of a completed window (coalesced, fire-and-forget)
    if ((s & (FB - 1)) == (FB - 1) || s == T - 1) {
      const int p = (s >> 5) & 1;
      const int rem = (s & (FB - 1)) + 1;     // steps in this window
      const int j = tid >> 3;                 // step-in-window 0..31
      const int cc = (tid & 7) * 8;           // 0..56
      if (j < rem) {
        f32x4 v0 = *reinterpret_cast<const f32x4*>(&hbuf[p][j][cc]);
        f32x4 v1 = *reinterpret_cast<const f32x4*>(&hbuf[p][j][cc + 4]);
        float* dst = hs_out + ((size_t)(s - rem + 1 + j) * BATCH + b) * NH + cc;
        *reinterpret_cast<f32x4*>(dst) = v0;
        *reinterpret_cast<f32x4*>(dst + 4) = v1;
      }
    }
    cur = nxt; nxt = fut;
  }
  if (l < 16) {
    float hfin = (float)reinterpret_cast<_Float16*>(h_lds[T & 1])[hidx];
    // recover full-precision final h from the last hbuf entry instead
    hfin = hbuf[((T - 1) >> 5) & 1][(T - 1) & (FB - 1)][hidx];
    h_state[b * NH + hidx] = hfin;
    c_state[b * NH + hidx] = creg;
    if (is_last) {
      hT_out[b * NH + hidx] = hfin;
      cT_out[b * NH + hidx] = creg;
    }
  }
}

// decoded[idx][j] = hs[idx][:] @ Wdec[:,j] + bdec[j], idx = s*BATCH+b
__global__ __launch_bounds__(256) void decode(
    const float* __restrict__ hs, const float* __restrict__ Wdec,
    const float* __restrict__ bdec, float* __restrict__ out, int n) {
  __shared__ float wl[NH * 3];
  __shared__ float bl[3];
  const int tid = threadIdx.x;
  if (tid < NH * 3) wl[tid] = Wdec[tid];
  if (tid < 3) bl[tid] = bdec[tid];
  __syncthreads();
  int idx = blockIdx.x * 256 + tid;
  if (idx >= n) return;
  const float* hp = hs + (size_t)idx * NH;
  float d0 = 0.f, d1 = 0.f, d2 = 0.f;
#pragma unroll
  for (int k = 0; k < NH; k += 4) {
    f32x4 h4 = *reinterpret_cast<const f32x4*>(&hp[k]);
#pragma unroll
    for (int j = 0; j < 4; ++j) {
      d0 += h4[j] * wl[(k + j) * 3 + 0];
      d1 += h4[j] * wl[(k + j) * 3 + 1];
      d2 += h4[j] * wl[(k + j) * 3 + 2];
    }
  }
  out[(size_t)idx * 3 + 0] = d0 + bl[0];
  out[(size_t)idx * 3 + 1] = d1 + bl[1];
  out[(size_t)idx * 3 + 2] = d2 + bl[2];
}

extern "C" void kernel_launch(void* const* d_in, const int* in_sizes, int n_in,
                              void* d_out, int out_size, void* d_ws, size_t ws_size,
                              hipStream_t stream) {
  const float* x    = (const float*)d_in[0];
  const float* h0   = (const float*)d_in[1];
  const float* c0   = (const float*)d_in[2];
  const float* Wpt0 = (const float*)d_in[3];
  const float* bpt0 = (const float*)d_in[4];
  const float* Wpt1 = (const float*)d_in[5];
  const float* bpt1 = (const float*)d_in[6];
  const float* Wglt = (const float*)d_in[7];
  const float* Wdec = (const float*)d_in[8];
  const float* bdec = (const float*)d_in[9];
  float* out = (float*)d_out;

  char* ws = (char*)d_ws;
  short*     WcatT   = (short*)(ws);              // 163840 B
  float*     bcat    = (float*)(ws + 163840);     // 1 KB
  _Float16*  Wg16    = (_Float16*)(ws + 164864);  // 32768 B (256 x 64 f16)
  float*     h_state = (float*)(ws + 197632);     // 64 KB
  float*     c_state = (float*)(ws + 263168);     // 64 KB
  const size_t base = 328704;

  // per-step chunk bytes: i2h (256*256*4) + hs (256*64*4)
  const size_t i2h_step = (size_t)BATCH * NG * 4;
  const size_t hs_step  = (size_t)BATCH * NH * 4;
  size_t avail = (ws_size > base) ? ws_size - base : 0;
  int T = (int)(avail / (i2h_step + hs_step));
  if (T > SLEN) T = SLEN;
  if (T < 1) T = 1;

  float* i2h = (float*)(ws + base);
  float* hs  = (float*)(ws + base + (size_t)T * i2h_step);

  prep_w<<<dim3((NG * KP + 255) / 256), dim3(256), 0, stream>>>(
      Wpt0, bpt0, Wpt1, bpt1, Wglt, WcatT, bcat, Wg16);

  for (int t0 = 0; t0 < SLEN; t0 += T) {
    int Tc = (SLEN - t0 < T) ? (SLEN - t0) : T;
    dim3 g(Tc * BATCH / BM, NG / BN);
    gemm_i2h<<<g, dim3(256), 0, stream>>>(
        x + (size_t)t0 * BATCH * NIN, WcatT, bcat, i2h);
    rec_seq<<<dim3(BATCH), dim3(256), 0, stream>>>(
        i2h, Wg16,
        (t0 == 0) ? h0 : h_state, (t0 == 0) ? c0 : c_state,
        h_state, c_state, hs,
        out + (size_t)SLEN * BATCH * 3,
        out + (size_t)SLEN * BATCH * 3 + BATCH * NH,
        Tc, (t0 + Tc >= SLEN) ? 1 : 0);
    decode<<<dim3((Tc * BATCH + 255) / 256), dim3(256), 0, stream>>>(
        hs, Wdec, bdec, out + (size_t)t0 * BATCH * 3, Tc * BATCH);
  }
}

// Round 6
// 474.897 us; speedup vs baseline: 1.0023x; 1.0023x over previous
//
#include <hip/hip_runtime.h>
#include <hip/hip_bf16.h>

#define SLEN 512
#define BATCH 256
#define NIN 300
#define KP 320
#define NG 256
#define NH 64
#define BM 128
#define BN 128
#define BK 64
#define LDP 72   // padded LDS row length (bf16) -> 144B rows, 2-way (free) b128 reads
#define RPB 2    // batch rows per rec block (8 waves, 2 waves/SIMD)

typedef float f32x4 __attribute__((ext_vector_type(4)));
typedef short s16x8 __attribute__((ext_vector_type(8)));
typedef short s16x4 __attribute__((ext_vector_type(4)));
typedef _Float16 f16x8 __attribute__((ext_vector_type(8)));
typedef _Float16 f16x2 __attribute__((ext_vector_type(2)));

__device__ __forceinline__ short f2bf(float f) {
  union { float f; unsigned u; } v; v.f = f;
  unsigned r = v.u + 0x7fffu + ((v.u >> 16) & 1u);  // RNE
  return (short)(r >> 16);
}

// Build WcatT[n][k] (bf16, K padded to 320), bcat[n], and Wg16[col][k] = f16(W_glt[k][col]).
__global__ void prep_w(const float* __restrict__ Wpt0, const float* __restrict__ bpt0,
                       const float* __restrict__ Wpt1, const float* __restrict__ bpt1,
                       const float* __restrict__ Wglt,
                       short* __restrict__ WcatT, float* __restrict__ bcat,
                       _Float16* __restrict__ Wg16) {
  int idx = blockIdx.x * 256 + threadIdx.x;
  if (idx < NG * KP) {
    int n = idx / KP, k = idx - n * KP;
    int g = n >> 6, h = n & 63;
    float w = 0.f;
    if (k < NIN) {
      if (h < 32) w = Wpt0[k * 128 + g * 32 + h];
      else        w = 0.5f * Wpt1[(k >> 1) * 128 + g * 32 + (h - 32)];
    }
    WcatT[idx] = f2bf(w);
  }
  if (idx < NG * NH) {  // transpose W_glt (64 x 256) -> Wg16 (256 x 64), f16
    int c = idx >> 6, k = idx & 63;
    Wg16[idx] = (_Float16)Wglt[k * NG + c];
  }
  if (idx < NG) {
    int g = idx >> 6, h = idx & 63;
    bcat[idx] = (h < 32) ? bpt0[g * 32 + h] : bpt1[g * 32 + h - 32];
  }
}

// C[row][n] = bf16(x[row]) @ WcatT^T + bcat   (row-chunk local)
__global__ __launch_bounds__(256) void gemm_i2h(
    const float* __restrict__ x, const short* __restrict__ WcatT,
    const float* __restrict__ bcat, float* __restrict__ C) {
  __shared__ short As[BM][LDP];
  __shared__ short Bs[BN][LDP];
  const int tid = threadIdx.x;
  const int m0 = blockIdx.x * BM;
  const int n0 = blockIdx.y * BN;
  const int lane = tid & 63;
  const int w = tid >> 6;
  const int wr = w >> 1, wc = w & 1;

  f32x4 acc[4][4];
#pragma unroll
  for (int m = 0; m < 4; ++m)
#pragma unroll
    for (int n = 0; n < 4; ++n) acc[m][n] = (f32x4){0.f, 0.f, 0.f, 0.f};

  const int arow_l = tid >> 4;        // 0..15
  const int acol   = (tid & 15) * 4;  // 0..60
  const int brow_l = tid >> 3;        // 0..31
  const int bcol   = (tid & 7) * 8;   // 0..56

  for (int k0 = 0; k0 < KP; k0 += BK) {
#pragma unroll
    for (int p = 0; p < 8; ++p) {
      int row = p * 16 + arow_l;
      int gk = k0 + acol;
      f32x4 v = (f32x4){0.f, 0.f, 0.f, 0.f};
      if (gk + 3 < NIN)  // 300 = 4*75 so vectors never straddle the boundary
        v = *reinterpret_cast<const f32x4*>(&x[(size_t)(m0 + row) * NIN + gk]);
      s16x4 sv;
      sv[0] = f2bf(v[0]); sv[1] = f2bf(v[1]); sv[2] = f2bf(v[2]); sv[3] = f2bf(v[3]);
      *reinterpret_cast<s16x4*>(&As[row][acol]) = sv;
    }
#pragma unroll
    for (int p = 0; p < 4; ++p) {
      int n = p * 32 + brow_l;
      s16x8 v = *reinterpret_cast<const s16x8*>(&WcatT[(size_t)(n0 + n) * KP + k0 + bcol]);
      *reinterpret_cast<s16x8*>(&Bs[n][bcol]) = v;
    }
    __syncthreads();
#pragma unroll
    for (int ks = 0; ks < 2; ++ks) {
      const int kk = ks * 32 + (lane >> 4) * 8;
      s16x8 a[4], b[4];
#pragma unroll
      for (int m = 0; m < 4; ++m)
        a[m] = *reinterpret_cast<const s16x8*>(&As[wr * 64 + m * 16 + (lane & 15)][kk]);
#pragma unroll
      for (int n = 0; n < 4; ++n)
        b[n] = *reinterpret_cast<const s16x8*>(&Bs[wc * 64 + n * 16 + (lane & 15)][kk]);
#pragma unroll
      for (int m = 0; m < 4; ++m)
#pragma unroll
        for (int n = 0; n < 4; ++n)
          acc[m][n] = __builtin_amdgcn_mfma_f32_16x16x32_bf16(a[m], b[n], acc[m][n], 0, 0, 0);
    }
    __syncthreads();
  }
  const int fc = lane & 15;
  const int fr = (lane >> 4) * 4;
#pragma unroll
  for (int n = 0; n < 4; ++n) {
    int col = n0 + wc * 64 + n * 16 + fc;
    float bias = bcat[col];
#pragma unroll
    for (int m = 0; m < 4; ++m) {
#pragma unroll
      for (int r = 0; r < 4; ++r) {
        int row = m0 + wr * 64 + m * 16 + fr + r;
        C[(size_t)row * NG + col] = acc[m][n][r] + bias;
      }
    }
  }
}

// RPB batch rows per block: 512 threads = 8 waves; waves 0-3 -> row 0, 4-7 -> row 1.
// Each SIMD hosts 2 waves from INDEPENDENT rows -> latency hiding.
// Within a row: wave ww, lane l: gate g = l>>4, hidden hidx = ww*16+(l&15).
// Weights staged in LDS [kk][col] (f16x8 entries, consecutive-lane-consecutive-entry
// = conflict-free); loaded to regs pre-loop, worst-case remat = cheap LDS re-read.
// One raw barrier per step (lgkmcnt only); hs stored directly (fire-and-forget).
__global__ __launch_bounds__(512, 2)
__attribute__((amdgpu_waves_per_eu(2, 2)))
void rec_seq(
    const float* __restrict__ i2h, const _Float16* __restrict__ Wg16,
    const float* __restrict__ h_in, const float* __restrict__ c_in,
    float* __restrict__ h_state, float* __restrict__ c_state,
    float* __restrict__ hs_out, float* __restrict__ hT_out, float* __restrict__ cT_out,
    int T, int is_last) {
  const int tid = threadIdx.x;
  const int wv = tid >> 6;          // 0..7
  const int rr = wv >> 2;           // row-in-block
  const int ww = wv & 3;            // wave-in-row
  const int l = tid & 63;
  const int g = l >> 4;
  const int hidx = ww * 16 + (l & 15);
  const int col = g * 64 + hidx;
  const int b = blockIdx.x * RPB + rr;

  __shared__ f16x8 Wlds[8][NG];       // 32 KB: [kk][col]
  __shared__ f16x8 h_lds[RPB][2][8];  // per-row double-buffered h (64 f16 each)

  // stage weights: entry e = kk*256 + col
  for (int e = tid; e < 8 * NG; e += 512) {
    int kk = e >> 8, c = e & 255;
    Wlds[kk][c] = *reinterpret_cast<const f16x8*>(Wg16 + (size_t)c * NH + kk * 8);
  }
  float creg = 0.f, hreg = 0.f;
  if (l < 16) creg = c_in[b * NH + hidx];
  if (tid < RPB * NH) {
    int r2 = tid >> 6, hh = tid & 63;
    reinterpret_cast<_Float16*>(&h_lds[r2][0][0])[hh] =
        (_Float16)h_in[(blockIdx.x * RPB + r2) * NH + hh];
  }
  __syncthreads();

  // per-thread weight registers (fallback remat source = LDS, not scratch)
  f16x8 w0 = Wlds[0][col], w1 = Wlds[1][col], w2 = Wlds[2][col], w3 = Wlds[3][col];
  f16x8 w4 = Wlds[4][col], w5 = Wlds[5][col], w6 = Wlds[6][col], w7 = Wlds[7][col];

  const float* ip = i2h + (size_t)b * NG + col;
  float cur = ip[0];
  float nxt = (T > 1) ? ip[(size_t)NG * BATCH] : 0.f;
  const float mm = (g == 1) ? 2.f : 1.f;

  for (int s = 0; s < T; ++s) {
    float fut = 0.f;
    if (s + 2 < T) fut = ip[(size_t)(s + 2) * NG * BATCH];  // stays in flight across barrier

    const f16x8* hb = h_lds[rr][s & 1];
    float acc0 = 0.f, acc1 = 0.f;
#define PAIR(v, j) __builtin_shufflevector(v, v, 2*(j), 2*(j)+1)
#define DOT(i, W) { f16x8 hv = hb[i]; \
      acc0 = __builtin_amdgcn_fdot2(PAIR(hv,0), PAIR(W,0), acc0, false); \
      acc1 = __builtin_amdgcn_fdot2(PAIR(hv,1), PAIR(W,1), acc1, false); \
      acc0 = __builtin_amdgcn_fdot2(PAIR(hv,2), PAIR(W,2), acc0, false); \
      acc1 = __builtin_amdgcn_fdot2(PAIR(hv,3), PAIR(W,3), acc1, false); }
    DOT(0, w0) DOT(1, w1) DOT(2, w2) DOT(3, w3)
    DOT(4, w4) DOT(5, w5) DOT(6, w6) DOT(7, w7)
    float pre = cur + (acc0 + acc1);

    // sigmoid for f,i,o; tanh (=2*sigmoid(2x)-1) for g; one exp either way
    float xx = fminf(fmaxf(pre, -30.f), 30.f);
    float e = __expf(-mm * xx);
    float y = 1.f / (1.f + e);
    float act = (g == 1) ? (2.f * y - 1.f) : y;

    // lanes 0..15 (g==0, holding f) gather g,i,o from lanes +16,+32,+48
    float g_ = __shfl(act, l + 16);
    float i_ = __shfl(act, l + 32);
    float o_ = __shfl(act, l + 48);

    if (l < 16) {
      float c1 = act * creg + i_ * g_;
      creg = c1;
      float ct = fminf(fmaxf(c1, -15.f), 15.f);
      float e2 = __expf(-2.f * ct);
      float th = (1.f - e2) / (1.f + e2);
      float h1 = o_ * th;
      hreg = h1;
      reinterpret_cast<_Float16*>(&h_lds[rr][(s + 1) & 1][0])[hidx] = (_Float16)h1;
      hs_out[((size_t)s * BATCH + b) * NH + hidx] = h1;  // fire-and-forget
    }
    // order the ds_write; global stores/prefetch stay outstanding
    asm volatile("s_waitcnt lgkmcnt(0)" ::: "memory");
    __builtin_amdgcn_s_barrier();
    cur = nxt; nxt = fut;
  }
  if (l < 16) {
    h_state[b * NH + hidx] = hreg;
    c_state[b * NH + hidx] = creg;
    if (is_last) {
      hT_out[b * NH + hidx] = hreg;
      cT_out[b * NH + hidx] = creg;
    }
  }
}

// decoded[idx][j] = hs[idx][:] @ Wdec[:,j] + bdec[j], idx = s*BATCH+b
__global__ __launch_bounds__(256) void decode(
    const float* __restrict__ hs, const float* __restrict__ Wdec,
    const float* __restrict__ bdec, float* __restrict__ out, int n) {
  __shared__ float wl[NH * 3];
  __shared__ float bl[3];
  const int tid = threadIdx.x;
  if (tid < NH * 3) wl[tid] = Wdec[tid];
  if (tid < 3) bl[tid] = bdec[tid];
  __syncthreads();
  int idx = blockIdx.x * 256 + tid;
  if (idx >= n) return;
  const float* hp = hs + (size_t)idx * NH;
  float d0 = 0.f, d1 = 0.f, d2 = 0.f;
#pragma unroll
  for (int k = 0; k < NH; k += 4) {
    f32x4 h4 = *reinterpret_cast<const f32x4*>(&hp[k]);
#pragma unroll
    for (int j = 0; j < 4; ++j) {
      d0 += h4[j] * wl[(k + j) * 3 + 0];
      d1 += h4[j] * wl[(k + j) * 3 + 1];
      d2 += h4[j] * wl[(k + j) * 3 + 2];
    }
  }
  out[(size_t)idx * 3 + 0] = d0 + bl[0];
  out[(size_t)idx * 3 + 1] = d1 + bl[1];
  out[(size_t)idx * 3 + 2] = d2 + bl[2];
}

extern "C" void kernel_launch(void* const* d_in, const int* in_sizes, int n_in,
                              void* d_out, int out_size, void* d_ws, size_t ws_size,
                              hipStream_t stream) {
  const float* x    = (const float*)d_in[0];
  const float* h0   = (const float*)d_in[1];
  const float* c0   = (const float*)d_in[2];
  const float* Wpt0 = (const float*)d_in[3];
  const float* bpt0 = (const float*)d_in[4];
  const float* Wpt1 = (const float*)d_in[5];
  const float* bpt1 = (const float*)d_in[6];
  const float* Wglt = (const float*)d_in[7];
  const float* Wdec = (const float*)d_in[8];
  const float* bdec = (const float*)d_in[9];
  float* out = (float*)d_out;

  char* ws = (char*)d_ws;
  short*     WcatT   = (short*)(ws);              // 163840 B
  float*     bcat    = (float*)(ws + 163840);     // 1 KB
  _Float16*  Wg16    = (_Float16*)(ws + 164864);  // 32768 B (256 x 64 f16)
  float*     h_state = (float*)(ws + 197632);     // 64 KB
  float*     c_state = (float*)(ws + 263168);     // 64 KB
  const size_t base = 328704;

  // per-step chunk bytes: i2h (256*256*4) + hs (256*64*4)
  const size_t i2h_step = (size_t)BATCH * NG * 4;
  const size_t hs_step  = (size_t)BATCH * NH * 4;
  size_t avail = (ws_size > base) ? ws_size - base : 0;
  int T = (int)(avail / (i2h_step + hs_step));
  if (T > SLEN) T = SLEN;
  if (T < 1) T = 1;

  float* i2h = (float*)(ws + base);
  float* hs  = (float*)(ws + base + (size_t)T * i2h_step);

  prep_w<<<dim3((NG * KP + 255) / 256), dim3(256), 0, stream>>>(
      Wpt0, bpt0, Wpt1, bpt1, Wglt, WcatT, bcat, Wg16);

  for (int t0 = 0; t0 < SLEN; t0 += T) {
    int Tc = (SLEN - t0 < T) ? (SLEN - t0) : T;
    dim3 g(Tc * BATCH / BM, NG / BN);
    gemm_i2h<<<g, dim3(256), 0, stream>>>(
        x + (size_t)t0 * BATCH * NIN, WcatT, bcat, i2h);
    rec_seq<<<dim3(BATCH / RPB), dim3(512), 0, stream>>>(
        i2h, Wg16,
        (t0 == 0) ? h0 : h_state, (t0 == 0) ? c0 : c_state,
        h_state, c_state, hs,
        out + (size_t)SLEN * BATCH * 3,
        out + (size_t)SLEN * BATCH * 3 + BATCH * NH,
        Tc, (t0 + Tc >= SLEN) ? 1 : 0);
    decode<<<dim3((Tc * BATCH + 255) / 256), dim3(256), 0, stream>>>(
        hs, Wdec, bdec, out + (size_t)t0 * BATCH * 3, Tc * BATCH);
  }
}

// Round 7
// 443.836 us; speedup vs baseline: 1.0724x; 1.0700x over previous
//
#include <hip/hip_runtime.h>
#include <hip/hip_bf16.h>

#define SLEN 512
#define BATCH 256
#define NIN 300
#define KP 320
#define NG 256
#define NH 64
#define BM 128
#define BN 128
#define BK 64
#define LDP 72   // padded LDS row length (bf16) -> 144B rows, 2-way (free) b128 reads

typedef float f32x4 __attribute__((ext_vector_type(4)));
typedef short s16x8 __attribute__((ext_vector_type(8)));
typedef short s16x4 __attribute__((ext_vector_type(4)));
typedef _Float16 f16x8 __attribute__((ext_vector_type(8)));
typedef _Float16 f16x2 __attribute__((ext_vector_type(2)));

__device__ __forceinline__ short f2bf(float f) {
  union { float f; unsigned u; } v; v.f = f;
  unsigned r = v.u + 0x7fffu + ((v.u >> 16) & 1u);  // RNE
  return (short)(r >> 16);
}

// Build WcatT[n][k] (bf16, K padded to 320), bcat[n], and Wg16[col][k] = f16(W_glt[k][col]).
__global__ void prep_w(const float* __restrict__ Wpt0, const float* __restrict__ bpt0,
                       const float* __restrict__ Wpt1, const float* __restrict__ bpt1,
                       const float* __restrict__ Wglt,
                       short* __restrict__ WcatT, float* __restrict__ bcat,
                       _Float16* __restrict__ Wg16) {
  int idx = blockIdx.x * 256 + threadIdx.x;
  if (idx < NG * KP) {
    int n = idx / KP, k = idx - n * KP;
    int g = n >> 6, h = n & 63;
    float w = 0.f;
    if (k < NIN) {
      if (h < 32) w = Wpt0[k * 128 + g * 32 + h];
      else        w = 0.5f * Wpt1[(k >> 1) * 128 + g * 32 + (h - 32)];
    }
    WcatT[idx] = f2bf(w);
  }
  if (idx < NG * NH) {  // transpose W_glt (64 x 256) -> Wg16 (256 x 64), f16
    int c = idx >> 6, k = idx & 63;
    Wg16[idx] = (_Float16)Wglt[k * NG + c];
  }
  if (idx < NG) {
    int g = idx >> 6, h = idx & 63;
    bcat[idx] = (h < 32) ? bpt0[g * 32 + h] : bpt1[g * 32 + h - 32];
  }
}

// C[row][n] = bf16(x[row]) @ WcatT^T + bcat   (row-chunk local)
__global__ __launch_bounds__(256) void gemm_i2h(
    const float* __restrict__ x, const short* __restrict__ WcatT,
    const float* __restrict__ bcat, float* __restrict__ C) {
  __shared__ short As[BM][LDP];
  __shared__ short Bs[BN][LDP];
  const int tid = threadIdx.x;
  const int m0 = blockIdx.x * BM;
  const int n0 = blockIdx.y * BN;
  const int lane = tid & 63;
  const int w = tid >> 6;
  const int wr = w >> 1, wc = w & 1;

  f32x4 acc[4][4];
#pragma unroll
  for (int m = 0; m < 4; ++m)
#pragma unroll
    for (int n = 0; n < 4; ++n) acc[m][n] = (f32x4){0.f, 0.f, 0.f, 0.f};

  const int arow_l = tid >> 4;        // 0..15
  const int acol   = (tid & 15) * 4;  // 0..60
  const int brow_l = tid >> 3;        // 0..31
  const int bcol   = (tid & 7) * 8;   // 0..56

  for (int k0 = 0; k0 < KP; k0 += BK) {
#pragma unroll
    for (int p = 0; p < 8; ++p) {
      int row = p * 16 + arow_l;
      int gk = k0 + acol;
      f32x4 v = (f32x4){0.f, 0.f, 0.f, 0.f};
      if (gk + 3 < NIN)  // 300 = 4*75 so vectors never straddle the boundary
        v = *reinterpret_cast<const f32x4*>(&x[(size_t)(m0 + row) * NIN + gk]);
      s16x4 sv;
      sv[0] = f2bf(v[0]); sv[1] = f2bf(v[1]); sv[2] = f2bf(v[2]); sv[3] = f2bf(v[3]);
      *reinterpret_cast<s16x4*>(&As[row][acol]) = sv;
    }
#pragma unroll
    for (int p = 0; p < 4; ++p) {
      int n = p * 32 + brow_l;
      s16x8 v = *reinterpret_cast<const s16x8*>(&WcatT[(size_t)(n0 + n) * KP + k0 + bcol]);
      *reinterpret_cast<s16x8*>(&Bs[n][bcol]) = v;
    }
    __syncthreads();
#pragma unroll
    for (int ks = 0; ks < 2; ++ks) {
      const int kk = ks * 32 + (lane >> 4) * 8;
      s16x8 a[4], b[4];
#pragma unroll
      for (int m = 0; m < 4; ++m)
        a[m] = *reinterpret_cast<const s16x8*>(&As[wr * 64 + m * 16 + (lane & 15)][kk]);
#pragma unroll
      for (int n = 0; n < 4; ++n)
        b[n] = *reinterpret_cast<const s16x8*>(&Bs[wc * 64 + n * 16 + (lane & 15)][kk]);
#pragma unroll
      for (int m = 0; m < 4; ++m)
#pragma unroll
        for (int n = 0; n < 4; ++n)
          acc[m][n] = __builtin_amdgcn_mfma_f32_16x16x32_bf16(a[m], b[n], acc[m][n], 0, 0, 0);
    }
    __syncthreads();
  }
  const int fc = lane & 15;
  const int fr = (lane >> 4) * 4;
#pragma unroll
  for (int n = 0; n < 4; ++n) {
    int col = n0 + wc * 64 + n * 16 + fc;
    float bias = bcat[col];
#pragma unroll
    for (int m = 0; m < 4; ++m) {
#pragma unroll
      for (int r = 0; r < 4; ++r) {
        int row = m0 + wr * 64 + m * 16 + fr + r;
        C[(size_t)row * NG + col] = acc[m][n][r] + bias;
      }
    }
  }
}

// One block (4 waves) per batch row, 1 block/CU.
// Wave ww, lane l: gate g = l>>4, hidden hidx = ww*16+(l&15), col = g*64+hidx.
// Weights are staged in LDS, read into 8 named f16x8 registers, and then the
// SAME LDS region is overwritten by the per-step h buffers (aliased). Remat of
// the weight ds_reads past that overwrite would be a miscompile -> the
// compiler MUST keep the weights in VGPRs (launch_bounds(256,4): 128-reg
// budget). This kills the per-step weight reload that saturated the LDS/L1
// pipe in rounds 4-6 (the ~1780 cyc/step wall).
__global__ __launch_bounds__(256, 4)
void rec_seq(
    const float* __restrict__ i2h, const _Float16* __restrict__ Wg16,
    const float* __restrict__ h_in, const float* __restrict__ c_in,
    float* __restrict__ h_state, float* __restrict__ c_state,
    float* __restrict__ hs_out, float* __restrict__ hT_out, float* __restrict__ cT_out,
    int T, int is_last) {
  const int b = blockIdx.x;
  const int tid = threadIdx.x;
  const int ww = tid >> 6;
  const int l = tid & 63;
  const int g = l >> 4;
  const int hidx = ww * 16 + (l & 15);
  const int col = g * 64 + hidx;

  // 32 KB raw LDS: first used to stage weights [kk][col] (f16x8 entries),
  // then bytes [0..256) are reused (ALIASED) as the double-buffered h.
  __shared__ __align__(16) char LB[8 * NG * 16];
  f16x8* Wst = reinterpret_cast<f16x8*>(LB);           // Wst[kk*256 + c]
  _Float16* hbuf = reinterpret_cast<_Float16*>(LB);    // hbuf[(s&1)*64 + hidx]

  // stage weights (once): entry e = kk*256 + c
  for (int e = tid; e < 8 * NG; e += 256) {
    int kk = e >> 8, c = e & 255;
    Wst[e] = *reinterpret_cast<const f16x8*>(Wg16 + (size_t)c * NH + kk * 8);
  }
  __syncthreads();

  // weights -> registers (the only read of Wst)
  f16x8 w0 = Wst[0 * NG + col], w1 = Wst[1 * NG + col];
  f16x8 w2 = Wst[2 * NG + col], w3 = Wst[3 * NG + col];
  f16x8 w4 = Wst[4 * NG + col], w5 = Wst[5 * NG + col];
  f16x8 w6 = Wst[6 * NG + col], w7 = Wst[7 * NG + col];

  float creg = 0.f, hreg = 0.f;
  if (l < 16) creg = c_in[b * NH + hidx];
  float h0v = (tid < NH) ? h_in[b * NH + tid] : 0.f;
  __syncthreads();   // all weight reads done before the overwrite below

  if (tid < NH) hbuf[tid] = (_Float16)h0v;   // clobbers Wst[0][0..15] region
  __syncthreads();

  const float* ip = i2h + (size_t)b * NG + col;
  float cur = ip[0];
  float nxt = (T > 1) ? ip[(size_t)NG * BATCH] : 0.f;
  const float mm = (g == 1) ? 2.f : 1.f;

  for (int s = 0; s < T; ++s) {
    float fut = 0.f;
    if (s + 2 < T) fut = ip[(size_t)(s + 2) * NG * BATCH];  // in flight across barrier

    const f16x8* hb = reinterpret_cast<const f16x8*>(hbuf + (s & 1) * NH);
    float acc0 = 0.f, acc1 = 0.f;
#define PAIR(v, j) __builtin_shufflevector(v, v, 2*(j), 2*(j)+1)
#define DOT(i, W) { f16x8 hv = hb[i]; \
      acc0 = __builtin_amdgcn_fdot2(PAIR(hv,0), PAIR(W,0), acc0, false); \
      acc1 = __builtin_amdgcn_fdot2(PAIR(hv,1), PAIR(W,1), acc1, false); \
      acc0 = __builtin_amdgcn_fdot2(PAIR(hv,2), PAIR(W,2), acc0, false); \
      acc1 = __builtin_amdgcn_fdot2(PAIR(hv,3), PAIR(W,3), acc1, false); }
    DOT(0, w0) DOT(1, w1) DOT(2, w2) DOT(3, w3)
    DOT(4, w4) DOT(5, w5) DOT(6, w6) DOT(7, w7)
    float pre = cur + (acc0 + acc1);

    // sigmoid for f,i,o; tanh (=2*sigmoid(2x)-1) for g; one exp either way
    float xx = fminf(fmaxf(pre, -30.f), 30.f);
    float e = __expf(-mm * xx);
    float y = 1.f / (1.f + e);
    float act = (g == 1) ? (2.f * y - 1.f) : y;

    // lanes 0..15 (g==0, holding f) gather g,i,o from lanes +16,+32,+48
    float g_ = __shfl(act, l + 16);
    float i_ = __shfl(act, l + 32);
    float o_ = __shfl(act, l + 48);

    if (l < 16) {
      float c1 = act * creg + i_ * g_;
      creg = c1;
      float ct = fminf(fmaxf(c1, -15.f), 15.f);
      float e2 = __expf(-2.f * ct);
      float th = (1.f - e2) / (1.f + e2);
      float h1 = o_ * th;
      hreg = h1;
      hbuf[((s + 1) & 1) * NH + hidx] = (_Float16)h1;
      hs_out[((size_t)s * BATCH + b) * NH + hidx] = h1;  // fire-and-forget
    }
    // order the ds_write; global stores/prefetch stay outstanding
    asm volatile("s_waitcnt lgkmcnt(0)" ::: "memory");
    __builtin_amdgcn_s_barrier();
    cur = nxt; nxt = fut;
  }
  if (l < 16) {
    h_state[b * NH + hidx] = hreg;
    c_state[b * NH + hidx] = creg;
    if (is_last) {
      hT_out[b * NH + hidx] = hreg;
      cT_out[b * NH + hidx] = creg;
    }
  }
}

// decoded[idx][j] = hs[idx][:] @ Wdec[:,j] + bdec[j], idx = s*BATCH+b
__global__ __launch_bounds__(256) void decode(
    const float* __restrict__ hs, const float* __restrict__ Wdec,
    const float* __restrict__ bdec, float* __restrict__ out, int n) {
  __shared__ float wl[NH * 3];
  __shared__ float bl[3];
  const int tid = threadIdx.x;
  if (tid < NH * 3) wl[tid] = Wdec[tid];
  if (tid < 3) bl[tid] = bdec[tid];
  __syncthreads();
  int idx = blockIdx.x * 256 + tid;
  if (idx >= n) return;
  const float* hp = hs + (size_t)idx * NH;
  float d0 = 0.f, d1 = 0.f, d2 = 0.f;
#pragma unroll
  for (int k = 0; k < NH; k += 4) {
    f32x4 h4 = *reinterpret_cast<const f32x4*>(&hp[k]);
#pragma unroll
    for (int j = 0; j < 4; ++j) {
      d0 += h4[j] * wl[(k + j) * 3 + 0];
      d1 += h4[j] * wl[(k + j) * 3 + 1];
      d2 += h4[j] * wl[(k + j) * 3 + 2];
    }
  }
  out[(size_t)idx * 3 + 0] = d0 + bl[0];
  out[(size_t)idx * 3 + 1] = d1 + bl[1];
  out[(size_t)idx * 3 + 2] = d2 + bl[2];
}

extern "C" void kernel_launch(void* const* d_in, const int* in_sizes, int n_in,
                              void* d_out, int out_size, void* d_ws, size_t ws_size,
                              hipStream_t stream) {
  const float* x    = (const float*)d_in[0];
  const float* h0   = (const float*)d_in[1];
  const float* c0   = (const float*)d_in[2];
  const float* Wpt0 = (const float*)d_in[3];
  const float* bpt0 = (const float*)d_in[4];
  const float* Wpt1 = (const float*)d_in[5];
  const float* bpt1 = (const float*)d_in[6];
  const float* Wglt = (const float*)d_in[7];
  const float* Wdec = (const float*)d_in[8];
  const float* bdec = (const float*)d_in[9];
  float* out = (float*)d_out;

  char* ws = (char*)d_ws;
  short*     WcatT   = (short*)(ws);              // 163840 B
  float*     bcat    = (float*)(ws + 163840);     // 1 KB
  _Float16*  Wg16    = (_Float16*)(ws + 164864);  // 32768 B (256 x 64 f16)
  float*     h_state = (float*)(ws + 197632);     // 64 KB
  float*     c_state = (float*)(ws + 263168);     // 64 KB
  const size_t base = 328704;

  // per-step chunk bytes: i2h (256*256*4) + hs (256*64*4)
  const size_t i2h_step = (size_t)BATCH * NG * 4;
  const size_t hs_step  = (size_t)BATCH * NH * 4;
  size_t avail = (ws_size > base) ? ws_size - base : 0;
  int T = (int)(avail / (i2h_step + hs_step));
  if (T > SLEN) T = SLEN;
  if (T < 1) T = 1;

  float* i2h = (float*)(ws + base);
  float* hs  = (float*)(ws + base + (size_t)T * i2h_step);

  prep_w<<<dim3((NG * KP + 255) / 256), dim3(256), 0, stream>>>(
      Wpt0, bpt0, Wpt1, bpt1, Wglt, WcatT, bcat, Wg16);

  for (int t0 = 0; t0 < SLEN; t0 += T) {
    int Tc = (SLEN - t0 < T) ? (SLEN - t0) : T;
    dim3 g(Tc * BATCH / BM, NG / BN);
    gemm_i2h<<<g, dim3(256), 0, stream>>>(
        x + (size_t)t0 * BATCH * NIN, WcatT, bcat, i2h);
    rec_seq<<<dim3(BATCH), dim3(256), 0, stream>>>(
        i2h, Wg16,
        (t0 == 0) ? h0 : h_state, (t0 == 0) ? c0 : c_state,
        h_state, c_state, hs,
        out + (size_t)SLEN * BATCH * 3,
        out + (size_t)SLEN * BATCH * 3 + BATCH * NH,
        Tc, (t0 + Tc >= SLEN) ? 1 : 0);
    decode<<<dim3((Tc * BATCH + 255) / 256), dim3(256), 0, stream>>>(
        hs, Wdec, bdec, out + (size_t)t0 * BATCH * 3, Tc * BATCH);
  }
}

// Round 8
// 322.865 us; speedup vs baseline: 1.4742x; 1.3747x over previous
//
#include <hip/hip_runtime.h>
#include <hip/hip_bf16.h>

#define SLEN 512
#define BATCH 256
#define NIN 300
#define KP 320
#define NG 256
#define NH 64
#define BM 128
#define BN 128
#define BK 64
#define LDP 72   // padded LDS row length (bf16) -> 144B rows, 2-way (free) b128 reads

typedef float f32x4 __attribute__((ext_vector_type(4)));
typedef short s16x8 __attribute__((ext_vector_type(8)));
typedef short s16x4 __attribute__((ext_vector_type(4)));
typedef _Float16 f16x8 __attribute__((ext_vector_type(8)));
typedef _Float16 f16x2 __attribute__((ext_vector_type(2)));

__device__ __forceinline__ short f2bf(float f) {
  union { float f; unsigned u; } v; v.f = f;
  unsigned r = v.u + 0x7fffu + ((v.u >> 16) & 1u);  // RNE
  return (short)(r >> 16);
}

// Build WcatT[n][k] (bf16, K padded to 320), bcat[n], and Wg16[col][k] = f16(W_glt[k][col]).
__global__ void prep_w(const float* __restrict__ Wpt0, const float* __restrict__ bpt0,
                       const float* __restrict__ Wpt1, const float* __restrict__ bpt1,
                       const float* __restrict__ Wglt,
                       short* __restrict__ WcatT, float* __restrict__ bcat,
                       _Float16* __restrict__ Wg16) {
  int idx = blockIdx.x * 256 + threadIdx.x;
  if (idx < NG * KP) {
    int n = idx / KP, k = idx - n * KP;
    int g = n >> 6, h = n & 63;
    float w = 0.f;
    if (k < NIN) {
      if (h < 32) w = Wpt0[k * 128 + g * 32 + h];
      else        w = 0.5f * Wpt1[(k >> 1) * 128 + g * 32 + (h - 32)];
    }
    WcatT[idx] = f2bf(w);
  }
  if (idx < NG * NH) {  // transpose W_glt (64 x 256) -> Wg16 (256 x 64), f16
    int c = idx >> 6, k = idx & 63;
    Wg16[idx] = (_Float16)Wglt[k * NG + c];
  }
  if (idx < NG) {
    int g = idx >> 6, h = idx & 63;
    bcat[idx] = (h < 32) ? bpt0[g * 32 + h] : bpt1[g * 32 + h - 32];
  }
}

// C[row][n] = bf16(x[row]) @ WcatT^T + bcat   (row-chunk local)
__global__ __launch_bounds__(256) void gemm_i2h(
    const float* __restrict__ x, const short* __restrict__ WcatT,
    const float* __restrict__ bcat, float* __restrict__ C) {
  __shared__ short As[BM][LDP];
  __shared__ short Bs[BN][LDP];
  const int tid = threadIdx.x;
  const int m0 = blockIdx.x * BM;
  const int n0 = blockIdx.y * BN;
  const int lane = tid & 63;
  const int w = tid >> 6;
  const int wr = w >> 1, wc = w & 1;

  f32x4 acc[4][4];
#pragma unroll
  for (int m = 0; m < 4; ++m)
#pragma unroll
    for (int n = 0; n < 4; ++n) acc[m][n] = (f32x4){0.f, 0.f, 0.f, 0.f};

  const int arow_l = tid >> 4;        // 0..15
  const int acol   = (tid & 15) * 4;  // 0..60
  const int brow_l = tid >> 3;        // 0..31
  const int bcol   = (tid & 7) * 8;   // 0..56

  for (int k0 = 0; k0 < KP; k0 += BK) {
#pragma unroll
    for (int p = 0; p < 8; ++p) {
      int row = p * 16 + arow_l;
      int gk = k0 + acol;
      f32x4 v = (f32x4){0.f, 0.f, 0.f, 0.f};
      if (gk + 3 < NIN)  // 300 = 4*75 so vectors never straddle the boundary
        v = *reinterpret_cast<const f32x4*>(&x[(size_t)(m0 + row) * NIN + gk]);
      s16x4 sv;
      sv[0] = f2bf(v[0]); sv[1] = f2bf(v[1]); sv[2] = f2bf(v[2]); sv[3] = f2bf(v[3]);
      *reinterpret_cast<s16x4*>(&As[row][acol]) = sv;
    }
#pragma unroll
    for (int p = 0; p < 4; ++p) {
      int n = p * 32 + brow_l;
      s16x8 v = *reinterpret_cast<const s16x8*>(&WcatT[(size_t)(n0 + n) * KP + k0 + bcol]);
      *reinterpret_cast<s16x8*>(&Bs[n][bcol]) = v;
    }
    __syncthreads();
#pragma unroll
    for (int ks = 0; ks < 2; ++ks) {
      const int kk = ks * 32 + (lane >> 4) * 8;
      s16x8 a[4], b[4];
#pragma unroll
      for (int m = 0; m < 4; ++m)
        a[m] = *reinterpret_cast<const s16x8*>(&As[wr * 64 + m * 16 + (lane & 15)][kk]);
#pragma unroll
      for (int n = 0; n < 4; ++n)
        b[n] = *reinterpret_cast<const s16x8*>(&Bs[wc * 64 + n * 16 + (lane & 15)][kk]);
#pragma unroll
      for (int m = 0; m < 4; ++m)
#pragma unroll
        for (int n = 0; n < 4; ++n)
          acc[m][n] = __builtin_amdgcn_mfma_f32_16x16x32_bf16(a[m], b[n], acc[m][n], 0, 0, 0);
    }
    __syncthreads();
  }
  const int fc = lane & 15;
  const int fr = (lane >> 4) * 4;
#pragma unroll
  for (int n = 0; n < 4; ++n) {
    int col = n0 + wc * 64 + n * 16 + fc;
    float bias = bcat[col];
#pragma unroll
    for (int m = 0; m < 4; ++m) {
#pragma unroll
      for (int r = 0; r < 4; ++r) {
        int row = m0 + wr * 64 + m * 16 + fr + r;
        C[(size_t)row * NG + col] = acc[m][n][r] + bias;
      }
    }
  }
}

// One block (4 waves) per batch row, 1 block/CU.
// Wave ww, lane l: gate g = l>>4, hidden hidx = ww*16+(l&15), col = g*64+hidx.
// Weights register-resident via the LDS-alias trick (round 7, verified VGPR=44).
// NEW (round 8): unroll x4 with an 8-deep register prefetch pipeline for i2h.
// The rotation copies now wait on loads issued one full quad-body (~2800 cyc)
// earlier, fully covering the ~900-cyc HBM latency that was exposed per-step.
__global__ __launch_bounds__(256, 4)
void rec_seq(
    const float* __restrict__ i2h, const _Float16* __restrict__ Wg16,
    const float* __restrict__ h_in, const float* __restrict__ c_in,
    float* __restrict__ h_state, float* __restrict__ c_state,
    float* __restrict__ hs_out, float* __restrict__ hT_out, float* __restrict__ cT_out,
    int T, int is_last) {
  const int b = blockIdx.x;
  const int tid = threadIdx.x;
  const int ww = tid >> 6;
  const int l = tid & 63;
  const int g = l >> 4;
  const int hidx = ww * 16 + (l & 15);
  const int col = g * 64 + hidx;

  // 32 KB raw LDS: stage weights [kk][col] (f16x8), then bytes [0..256) are
  // reused (ALIASED) as the double-buffered h. Remat past the overwrite would
  // be a miscompile -> weights must stay in VGPRs.
  __shared__ __align__(16) char LB[8 * NG * 16];
  f16x8* Wst = reinterpret_cast<f16x8*>(LB);           // Wst[kk*256 + c]
  _Float16* hbuf = reinterpret_cast<_Float16*>(LB);    // hbuf[(s&1)*64 + hidx]

  for (int e = tid; e < 8 * NG; e += 256) {
    int kk = e >> 8, c = e & 255;
    Wst[e] = *reinterpret_cast<const f16x8*>(Wg16 + (size_t)c * NH + kk * 8);
  }
  __syncthreads();

  f16x8 w0 = Wst[0 * NG + col], w1 = Wst[1 * NG + col];
  f16x8 w2 = Wst[2 * NG + col], w3 = Wst[3 * NG + col];
  f16x8 w4 = Wst[4 * NG + col], w5 = Wst[5 * NG + col];
  f16x8 w6 = Wst[6 * NG + col], w7 = Wst[7 * NG + col];

  float creg = 0.f, hreg = 0.f;
  if (l < 16) creg = c_in[b * NH + hidx];
  float h0v = (tid < NH) ? h_in[b * NH + tid] : 0.f;
  __syncthreads();   // all weight reads done before the overwrite below

  if (tid < NH) hbuf[tid] = (_Float16)h0v;   // clobbers weight region
  __syncthreads();

  const size_t st = (size_t)NG * BATCH;
  const float* ip = i2h + (size_t)b * NG + col;
  float* hp = hs_out + (size_t)b * NH + hidx;
  const float mm = (g == 1) ? 2.f : 1.f;

#define PAIR(v, j) __builtin_shufflevector(v, v, 2*(j), 2*(j)+1)
#define DOT(hb, i, W) { f16x8 hv = (hb)[i]; \
      acc0 = __builtin_amdgcn_fdot2(PAIR(hv,0), PAIR(W,0), acc0, false); \
      acc1 = __builtin_amdgcn_fdot2(PAIR(hv,1), PAIR(W,1), acc1, false); \
      acc0 = __builtin_amdgcn_fdot2(PAIR(hv,2), PAIR(W,2), acc0, false); \
      acc1 = __builtin_amdgcn_fdot2(PAIR(hv,3), PAIR(W,3), acc1, false); }

#define STEP(CUR, SP) { \
    const f16x8* hb = reinterpret_cast<const f16x8*>(hbuf + ((SP) & 1) * NH); \
    float acc0 = 0.f, acc1 = 0.f; \
    DOT(hb, 0, w0) DOT(hb, 1, w1) DOT(hb, 2, w2) DOT(hb, 3, w3) \
    DOT(hb, 4, w4) DOT(hb, 5, w5) DOT(hb, 6, w6) DOT(hb, 7, w7) \
    float pre = (CUR) + (acc0 + acc1); \
    float xx = fminf(fmaxf(pre, -30.f), 30.f); \
    float e = __expf(-mm * xx); \
    float y = 1.f / (1.f + e); \
    float act = (g == 1) ? (2.f * y - 1.f) : y; \
    float g_ = __shfl(act, l + 16); \
    float i_ = __shfl(act, l + 32); \
    float o_ = __shfl(act, l + 48); \
    if (l < 16) { \
      float c1 = act * creg + i_ * g_; \
      creg = c1; \
      float ct = fminf(fmaxf(c1, -15.f), 15.f); \
      float e2 = __expf(-2.f * ct); \
      float th = (1.f - e2) / (1.f + e2); \
      float h1 = o_ * th; \
      hreg = h1; \
      hbuf[(((SP) + 1) & 1) * NH + hidx] = (_Float16)h1; \
      *hp = h1;  /* fire-and-forget */ \
    } \
    hp += st >> 2; /* BATCH*NH floats */ \
    asm volatile("s_waitcnt lgkmcnt(0)" ::: "memory"); \
    __builtin_amdgcn_s_barrier(); }

  int s = 0;
  if (T >= 8) {
    float c0v = ip[0],      c1v = ip[st],     c2v = ip[2 * st], c3v = ip[3 * st];
    float n0v = ip[4 * st], n1v = ip[5 * st], n2v = ip[6 * st], n3v = ip[7 * st];
    const float* ipf = ip + 8 * st;
    while (s + 4 <= T) {
      float f0v = (s + 8  < T) ? ipf[0]      : 0.f;
      float f1v = (s + 9  < T) ? ipf[st]     : 0.f;
      float f2v = (s + 10 < T) ? ipf[2 * st] : 0.f;
      float f3v = (s + 11 < T) ? ipf[3 * st] : 0.f;
      ipf += 4 * st;
      STEP(c0v, s)
      STEP(c1v, s + 1)
      STEP(c2v, s + 2)
      STEP(c3v, s + 3)
      c0v = n0v; c1v = n1v; c2v = n2v; c3v = n3v;   // waits: loads 1 quad old
      n0v = f0v; n1v = f1v; n2v = f2v; n3v = f3v;   // waits: loads this quad top
      s += 4;
    }
    if (s < T) { STEP(c0v, s) s++; }
    if (s < T) { STEP(c1v, s) s++; }
    if (s < T) { STEP(c2v, s) s++; }
  } else {
    while (s < T) { float cv = ip[(size_t)s * st]; STEP(cv, s) s++; }
  }

  if (l < 16) {
    h_state[b * NH + hidx] = hreg;
    c_state[b * NH + hidx] = creg;
    if (is_last) {
      hT_out[b * NH + hidx] = hreg;
      cT_out[b * NH + hidx] = creg;
    }
  }
}

// decoded[idx][j] = hs[idx][:] @ Wdec[:,j] + bdec[j], idx = s*BATCH+b
__global__ __launch_bounds__(256) void decode(
    const float* __restrict__ hs, const float* __restrict__ Wdec,
    const float* __restrict__ bdec, float* __restrict__ out, int n) {
  __shared__ float wl[NH * 3];
  __shared__ float bl[3];
  const int tid = threadIdx.x;
  if (tid < NH * 3) wl[tid] = Wdec[tid];
  if (tid < 3) bl[tid] = bdec[tid];
  __syncthreads();
  int idx = blockIdx.x * 256 + tid;
  if (idx >= n) return;
  const float* hp = hs + (size_t)idx * NH;
  float d0 = 0.f, d1 = 0.f, d2 = 0.f;
#pragma unroll
  for (int k = 0; k < NH; k += 4) {
    f32x4 h4 = *reinterpret_cast<const f32x4*>(&hp[k]);
#pragma unroll
    for (int j = 0; j < 4; ++j) {
      d0 += h4[j] * wl[(k + j) * 3 + 0];
      d1 += h4[j] * wl[(k + j) * 3 + 1];
      d2 += h4[j] * wl[(k + j) * 3 + 2];
    }
  }
  out[(size_t)idx * 3 + 0] = d0 + bl[0];
  out[(size_t)idx * 3 + 1] = d1 + bl[1];
  out[(size_t)idx * 3 + 2] = d2 + bl[2];
}

extern "C" void kernel_launch(void* const* d_in, const int* in_sizes, int n_in,
                              void* d_out, int out_size, void* d_ws, size_t ws_size,
                              hipStream_t stream) {
  const float* x    = (const float*)d_in[0];
  const float* h0   = (const float*)d_in[1];
  const float* c0   = (const float*)d_in[2];
  const float* Wpt0 = (const float*)d_in[3];
  const float* bpt0 = (const float*)d_in[4];
  const float* Wpt1 = (const float*)d_in[5];
  const float* bpt1 = (const float*)d_in[6];
  const float* Wglt = (const float*)d_in[7];
  const float* Wdec = (const float*)d_in[8];
  const float* bdec = (const float*)d_in[9];
  float* out = (float*)d_out;

  char* ws = (char*)d_ws;
  short*     WcatT   = (short*)(ws);              // 163840 B
  float*     bcat    = (float*)(ws + 163840);     // 1 KB
  _Float16*  Wg16    = (_Float16*)(ws + 164864);  // 32768 B (256 x 64 f16)
  float*     h_state = (float*)(ws + 197632);     // 64 KB
  float*     c_state = (float*)(ws + 263168);     // 64 KB
  const size_t base = 328704;

  // per-step chunk bytes: i2h (256*256*4) + hs (256*64*4)
  const size_t i2h_step = (size_t)BATCH * NG * 4;
  const size_t hs_step  = (size_t)BATCH * NH * 4;
  size_t avail = (ws_size > base) ? ws_size - base : 0;
  int T = (int)(avail / (i2h_step + hs_step));
  if (T > SLEN) T = SLEN;
  if (T < 1) T = 1;

  float* i2h = (float*)(ws + base);
  float* hs  = (float*)(ws + base + (size_t)T * i2h_step);

  prep_w<<<dim3((NG * KP + 255) / 256), dim3(256), 0, stream>>>(
      Wpt0, bpt0, Wpt1, bpt1, Wglt, WcatT, bcat, Wg16);

  for (int t0 = 0; t0 < SLEN; t0 += T) {
    int Tc = (SLEN - t0 < T) ? (SLEN - t0) : T;
    dim3 g(Tc * BATCH / BM, NG / BN);
    gemm_i2h<<<g, dim3(256), 0, stream>>>(
        x + (size_t)t0 * BATCH * NIN, WcatT, bcat, i2h);
    rec_seq<<<dim3(BATCH), dim3(256), 0, stream>>>(
        i2h, Wg16,
        (t0 == 0) ? h0 : h_state, (t0 == 0) ? c0 : c_state,
        h_state, c_state, hs,
        out + (size_t)SLEN * BATCH * 3,
        out + (size_t)SLEN * BATCH * 3 + BATCH * NH,
        Tc, (t0 + Tc >= SLEN) ? 1 : 0);
    decode<<<dim3((Tc * BATCH + 255) / 256), dim3(256), 0, stream>>>(
        hs, Wdec, bdec, out + (size_t)t0 * BATCH * 3, Tc * BATCH);
  }
}